// Round 9
// baseline (531.468 us; speedup 1.0000x reference)
//
#include <hip/hip_runtime.h>
#include <math.h>

// BiCGStab, 8 independent 512x512 images, single persistent kernel.
// 512 blocks x 512 threads (2 blocks/CU; capacity == grid => all resident).
// Block = 8 contiguous rows; thread = 2 rows x 4 cols => ~105 live VGPRs,
// fits the 128-VGPR cap (launch_bounds(512,4)) with NO scratch spills.
// All fields (x,p,r,r0,v) + coefficients in registers; s in LDS; t recomputed.
// TWO syncs per iteration (c4 reductions folded into P2 algebraically).
// Sync: fence-free aggregator protocol (round-8 validated). Blocks post
// partials (relaxed agent atomics, value|epoch packed); block sub==0 of each
// image polls+reduces them once, publishes sums into ONE 64B line; the other
// 63 blocks poll that single line. __syncthreads drains vmcnt before posts.

namespace {

typedef unsigned long long ull;

constexpr int NIMG = 8;
constexpr int NSd  = 512;
constexpr int S    = NSd*NSd;
constexpr int NSF  = NIMG*S;
constexpr int PADS = 514;
constexpr int NB   = 512;
constexpr int IPB  = 64;     // blocks per image
constexpr int NT   = 512;
constexpr float EPSF = 1e-9f;
constexpr float THR  = 1e-9f * 262144.0f;
constexpr float RX_=50.f, RY_=50.f, RXX_=100.f, RYY_=100.f;
constexpr float BOO0 = 1.f + 2.f*(RXX_+RYY_);

enum { P_PH=0, P_VH, P_TH, NPLH };                 // halo planes (atomic qwords)
constexpr size_t A_QW = (size_t)NIMG*2*8*64;       // 8192 qwords (64 KB)
constexpr size_t B_QW = (size_t)NIMG*2*8;          // 128 qwords (1 KB)

__device__ __forceinline__ int cl(int i){ return i<0?0:(i>NSd-1?NSd-1:i); }

#define LD4(d, p) { float4 _t4 = *reinterpret_cast<const float4*>(p); \
  (d)[0]=_t4.x; (d)[1]=_t4.y; (d)[2]=_t4.z; (d)[3]=_t4.w; }
#define ST4(p, s) { *reinterpret_cast<float4*>(p) = \
  make_float4((s)[0],(s)[1],(s)[2],(s)[3]); }
#define CP4(d, s) { (d)[0]=(s)[0]; (d)[1]=(s)[1]; (d)[2]=(s)[2]; (d)[3]=(s)[3]; }

// ---- coherent halo row I/O (relaxed agent atomics, 2 floats per qword) ----
__device__ __forceinline__ void hstore4(ull* pq, int off_f, const float s[4]){
  size_t q = (size_t)off_f >> 1;
  ull u0 = ((ull)__float_as_uint(s[1])<<32) | (ull)__float_as_uint(s[0]);
  ull u1 = ((ull)__float_as_uint(s[3])<<32) | (ull)__float_as_uint(s[2]);
  __hip_atomic_store(pq+q,   u0, __ATOMIC_RELAXED, __HIP_MEMORY_SCOPE_AGENT);
  __hip_atomic_store(pq+q+1, u1, __ATOMIC_RELAXED, __HIP_MEMORY_SCOPE_AGENT);
}
__device__ __forceinline__ void hload4(const ull* pq, int off_f, float d[4]){
  size_t q = (size_t)off_f >> 1;
  ull u0 = __hip_atomic_load(pq+q,   __ATOMIC_RELAXED, __HIP_MEMORY_SCOPE_AGENT);
  ull u1 = __hip_atomic_load(pq+q+1, __ATOMIC_RELAXED, __HIP_MEMORY_SCOPE_AGENT);
  d[0]=__uint_as_float((unsigned)u0); d[1]=__uint_as_float((unsigned)(u0>>32));
  d[2]=__uint_as_float((unsigned)u1); d[3]=__uint_as_float((unsigned)(u1>>32));
}

// ---- aggregator phase sync: post -> (sub0 reduces+publishes) -> broadcast ----
__device__ __forceinline__ void phase_sync(ull* Aq, ull* Bq, int img, int sub,
    unsigned ep, float* v, int n){
  __shared__ float acc[8][5];
  __shared__ float bc[5];
  const int tid = threadIdx.x, w = tid>>6, lane = tid&63;
  #pragma unroll
  for (int i=0;i<5;++i){
    if (i<n){
      float a = v[i];
      #pragma unroll
      for (int o=32;o;o>>=1) a += __shfl_xor(a,o);
      if (lane==0) acc[w][i] = a;
    }
  }
  __syncthreads();   // acc ready; drains vmcnt (halo stores globally visible)
  const int par = ep & 1;
  ull* Ab = Aq + ((size_t)(img*2+par)*8)*64;   // [sum][64] qwords, 512B rows
  ull* Bb = Bq + ((size_t)(img*2+par))*8;      // one 64B line
  if (sub == 0){
    if (w < n){
      float own = 0.f;
      #pragma unroll
      for (int i=0;i<8;++i) own += acc[i][w];
      ull x = 0; const bool me = (lane>=1);
      for(;;){
        bool ok = true;
        if (me){
          x = __hip_atomic_load(Ab + w*64 + lane, __ATOMIC_RELAXED, __HIP_MEMORY_SCOPE_AGENT);
          ok = ((unsigned)x == ep);
        }
        if (__all(ok)) break;
        __builtin_amdgcn_s_sleep(2);
      }
      float a = me ? __uint_as_float((unsigned)(x>>32)) : own;
      #pragma unroll
      for (int o=32;o;o>>=1) a += __shfl_xor(a,o);
      if (lane==0){
        bc[w] = a;
        ull pk = ((ull)__float_as_uint(a)<<32) | (ull)ep;
        __hip_atomic_store(Bb + w, pk, __ATOMIC_RELAXED, __HIP_MEMORY_SCOPE_AGENT);
      }
    }
  } else {
    if (tid < n){
      float t = 0.f;
      #pragma unroll
      for (int i=0;i<8;++i) t += acc[i][tid];
      ull pk = ((ull)__float_as_uint(t)<<32) | (ull)ep;
      __hip_atomic_store(Ab + tid*64 + sub, pk, __ATOMIC_RELAXED, __HIP_MEMORY_SCOPE_AGENT);
    }
    if (w == 0){
      ull x = 0; const bool me = (lane < n);
      for(;;){
        bool ok = true;
        if (me){
          x = __hip_atomic_load(Bb + lane, __ATOMIC_RELAXED, __HIP_MEMORY_SCOPE_AGENT);
          ok = ((unsigned)x == ep);
        }
        if (__all(ok)) break;
        __builtin_amdgcn_s_sleep(2);
      }
      if (me) bc[lane] = __uint_as_float((unsigned)(x>>32));
    }
  }
  __syncthreads();
  #pragma unroll
  for (int i=0;i<5;++i) if (i<n) v[i] = bc[i];
}

// 5-point stencil, center strip from registers; reference summation order
__device__ __forceinline__ void stencil_reg(const float zc[4], float zl, float zr,
    const float zu[4], const float zd[4],
    const float ax[4], float axl, const float by[4], const float bym[4],
    float out[4]){
  #pragma unroll
  for (int j=0;j<4;++j){
    float axm = j ? ax[j-1] : axl;
    float zxm = j ? zc[j-1] : zl;
    float zxp = (j<3) ? zc[j+1] : zr;
    float boo = BOO0 + ax[j] - axm + by[j] - bym[j];
    out[j] = boo*zc[j] + (-RXX_-axm)*zxm + (-RYY_-bym[j])*zu[j]
           + (-RYY_+by[j])*zd[j] + (-RXX_+ax[j])*zxp;
  }
}

__global__ void __launch_bounds__(NT, 4)
solve(const float* __restrict__ Vg,
    const float* __restrict__ M1g, const float* __restrict__ M2g,
    const int* __restrict__ kmp, float* __restrict__ outg, float* __restrict__ ws){
  __shared__ float tile[10][NSd];        // 20480 B; reused as [8][516] at pack
  const int tid = threadIdx.x, blk = blockIdx.x;
  const int img = blk & 7, sub = blk >> 3;       // 64 blocks per image
  const int y0 = sub*8, bS = img*S;
  const int cg = tid & 127, r0b = tid >> 7, c4o = cg*4;
  const int lane = tid & 63;
  ull* PHq = (ull*)(ws + (size_t)P_PH*NSF);
  ull* VHq = (ull*)(ws + (size_t)P_VH*NSF);
  ull* THq = (ull*)(ws + (size_t)P_TH*NSF);
  ull* Aq  = (ull*)(ws + (size_t)NPLH*NSF);
  ull* Bq  = Aq + A_QW;
  unsigned ep = 0;
  const int kmax = kmp[0];
  const int row0o  = bS + (y0<<9) + c4o;       // row y0   (published by r0b==0)
  const int row7o  = bS + ((y0+7)<<9) + c4o;   // row y0+7 (published by r0b==3)
  const int rowm1o = bS + ((y0-1)<<9) + c4o;   // valid only if sub>0
  const int row8o  = bS + ((y0+8)<<9) + c4o;   // valid only if sub<63
  float red[5];

  // ---- setup: coefficients into registers (rows y0 + 2*r0b + k, k=0,1) ----
  float ax_[2][4], axl_[2], by_[2][4], bym0_[4];
  float msum = 0.f;
  #pragma unroll
  for (int k=0;k<2;++k){
    int fy = y0 + 2*r0b + k, ro = bS + (fy<<9);
    float vc[4], vd[4], m1[4], m2[4];
    LD4(vc, Vg+ro+c4o);
    float vr  = Vg[ro + (c4o<508 ? c4o+4 : 511)];
    float vl  = c4o ? Vg[ro+c4o-1]  : vc[0];
    float m1l = c4o ? M1g[ro+c4o-1] : 0.f;
    LD4(vd, Vg + bS + (cl(fy+1)<<9) + c4o);
    LD4(m1, M1g+ro+c4o);
    LD4(m2, M2g+ro+c4o);
    #pragma unroll
    for (int j=0;j<4;++j){
      float vn = (j<3) ? vc[j+1] : vr;
      ax_[k][j] = RX_*((vn-vc[j])/(0.5f*(vn+vc[j])))*m1[j];
      by_[k][j] = RY_*((vd[j]-vc[j])/(0.5f*(vd[j]+vc[j])))*m2[j];
      msum += vc[j];
    }
    axl_[k] = c4o ? RX_*((vc[0]-vl)/(0.5f*(vc[0]+vl)))*m1l : 0.f;
    if (k==0){
      if (fy > 0){
        float vu[4], m2u[4];
        LD4(vu, Vg + bS + ((fy-1)<<9) + c4o);
        LD4(m2u, M2g + bS + ((fy-1)<<9) + c4o);
        #pragma unroll
        for (int j=0;j<4;++j)
          bym0_[j] = RY_*((vc[j]-vu[j])/(0.5f*(vc[j]+vu[j])))*m2u[j];
      } else {
        bym0_[0]=0.f; bym0_[1]=0.f; bym0_[2]=0.f; bym0_[3]=0.f;
      }
    }
  }
  red[0]=msum;
  ++ep; phase_sync(Aq,Bq,img,sub,ep, red, 1);
  const float c = red[0]*(1.0f/262144.0f);

  // ---- init: x=c, p=r=r0 = b - A(c) = -2c(ax-axm+by-bym) ----
  float x_[2][4], p_[2][4], r_[2][4], r0_[2][4], v_[2][4];
  float ph_[4], rh_[4], xh_[4], vh_[4];   // halo-row mirrors (r0b 0/3)
  {
    float pa = 0.f;
    #pragma unroll
    for (int k=0;k<2;++k){
      const float* bymk = k ? by_[0] : bym0_;
      #pragma unroll
      for (int j=0;j<4;++j){
        float axm = j ? ax_[k][j-1] : axl_[k];
        float pn = -2.f*c*(ax_[k][j]-axm + by_[k][j]-bymk[j]);
        x_[k][j]=c; p_[k][j]=pn; r_[k][j]=pn; r0_[k][j]=pn; v_[k][j]=0.f;
        pa += pn*pn;
      }
    }
    #pragma unroll
    for (int j=0;j<4;++j){ xh_[j]=c; ph_[j]=0.f; rh_[j]=0.f; vh_[j]=0.f; }
    if (r0b==0) hstore4(PHq, row0o, p_[0]);
    if (r0b==3) hstore4(PHq, row7o, p_[1]);
    red[0]=pa;
    ++ep; phase_sync(Aq,Bq,img,sub,ep, red, 1);
  }
  float rr0 = red[0];
  float r0abs = sqrtf(rr0), rabs = r0abs;
  int kcnt = 0;
  bool c4p = false;
  float alpha=0.f, omega=0.f, beta=0.f;

  for (int it=0; it<kmax; ++it){
    if (!((kcnt < kmax) && (rabs > THR))) break;

    // ================= P1: p-update; v = A(p); <v,r0>, <v,v> =================
    if (c4p){
      #pragma unroll
      for (int k=0;k<2;++k)
        #pragma unroll
        for (int j=0;j<4;++j)
          p_[k][j] = r_[k][j] + beta*(p_[k][j]-omega*v_[k][j]);
      if (r0b==0 || r0b==3){
        #pragma unroll
        for (int j=0;j<4;++j) ph_[j] = rh_[j] + beta*(ph_[j]-omega*vh_[j]);
      }
    } else {
      // after init/restart: r==p; refresh mirrors from PH (or own row)
      if (r0b==0){
        if (sub==0){ CP4(ph_, p_[0]); } else hload4(PHq, rowm1o, ph_);
        CP4(rh_, ph_);
      }
      if (r0b==3){
        if (sub==IPB-1){ CP4(ph_, p_[1]); } else hload4(PHq, row8o, ph_);
        CP4(rh_, ph_);
      }
    }
    #pragma unroll
    for (int k=0;k<2;++k){ ST4(&tile[2*r0b+k+1][c4o], p_[k]); }
    if (r0b==0) ST4(&tile[0][c4o], ph_);
    if (r0b==3) ST4(&tile[9][c4o], ph_);
    __syncthreads();
    {
      float s1=0.f, s2=0.f;
      #pragma unroll
      for (int k=0;k<2;++k){
        int st = 2*r0b+k+1;
        const float* bymk = k ? by_[0] : bym0_;
        float zu[4], zd[4], ov[4];
        LD4(zu, &tile[st-1][c4o]);
        LD4(zd, &tile[st+1][c4o]);
        float zl = __shfl_up(p_[k][3], 1);
        float zr = __shfl_down(p_[k][0], 1);
        if (lane==0)  zl = (c4o==0)   ? p_[k][0] : tile[st][c4o-1];
        if (lane==63) zr = (c4o==508) ? p_[k][3] : tile[st][c4o+4];
        stencil_reg(p_[k], zl, zr, zu, zd, ax_[k], axl_[k], by_[k], bymk, ov);
        #pragma unroll
        for (int j=0;j<4;++j){
          v_[k][j]=ov[j]; s1 += ov[j]*r0_[k][j]; s2 += ov[j]*ov[j];
        }
      }
      if (r0b==0) hstore4(VHq, row0o, v_[0]);
      if (r0b==3) hstore4(VHq, row7o, v_[1]);
      red[0]=s1; red[1]=s2;
      ++ep; phase_sync(Aq,Bq,img,sub,ep, red, 2);
    }
    float sig = red[0], vabs = sqrtf(red[1]);

    if (sig <= EPSF*vabs*r0abs){
      // ---- restart: p = r = r0 = b - A(x) ----
      #pragma unroll
      for (int k=0;k<2;++k){ ST4(&tile[2*r0b+k+1][c4o], x_[k]); }
      if (r0b==0) ST4(&tile[0][c4o], xh_);
      if (r0b==3) ST4(&tile[9][c4o], xh_);
      __syncthreads();
      float pa = 0.f;
      #pragma unroll
      for (int k=0;k<2;++k){
        int st = 2*r0b+k+1;
        const float* bymk = k ? by_[0] : bym0_;
        float zu[4], zd[4], av[4];
        LD4(zu, &tile[st-1][c4o]);
        LD4(zd, &tile[st+1][c4o]);
        float zl = __shfl_up(x_[k][3], 1);
        float zr = __shfl_down(x_[k][0], 1);
        if (lane==0)  zl = (c4o==0)   ? x_[k][0] : tile[st][c4o-1];
        if (lane==63) zr = (c4o==508) ? x_[k][3] : tile[st][c4o+4];
        stencil_reg(x_[k], zl, zr, zu, zd, ax_[k], axl_[k], by_[k], bymk, av);
        #pragma unroll
        for (int j=0;j<4;++j){
          float pn = c - av[j];
          p_[k][j]=pn; r_[k][j]=pn; r0_[k][j]=pn;
          pa += pn*pn;
        }
      }
      if (r0b==0) hstore4(PHq, row0o, p_[0]);
      if (r0b==3) hstore4(PHq, row7o, p_[1]);
      red[0]=pa;
      ++ep; phase_sync(Aq,Bq,img,sub,ep, red, 1);
      rr0 = red[0]; r0abs = sqrtf(rr0); rabs = r0abs; kcnt++;
      c4p = false;
      continue;
    }

    // ================= P2: s; t=A(s); 5 sums (c4 folded in) =================
    alpha = rr0 / sig;
    if (r0b==0){
      if (sub==0){ CP4(vh_, v_[0]); } else hload4(VHq, rowm1o, vh_);
    }
    if (r0b==3){
      if (sub==IPB-1){ CP4(vh_, v_[1]); } else hload4(VHq, row8o, vh_);
    }
    float t0s[4], t1s[4];
    {
      float ssp = 0.f;
      #pragma unroll
      for (int k=0;k<2;++k){
        float sv[4];
        #pragma unroll
        for (int j=0;j<4;++j){
          sv[j] = r_[k][j] - alpha*v_[k][j];
          ssp += sv[j]*sv[j];
        }
        ST4(&tile[2*r0b+k+1][c4o], sv);
      }
      if (r0b==0){
        float sh[4];
        #pragma unroll
        for (int j=0;j<4;++j) sh[j] = rh_[j] - alpha*vh_[j];
        ST4(&tile[0][c4o], sh);
      }
      if (r0b==3){
        float sh[4];
        #pragma unroll
        for (int j=0;j<4;++j) sh[j] = rh_[j] - alpha*vh_[j];
        ST4(&tile[9][c4o], sh);
      }
      __syncthreads();
      float tsp=0.f, ttp=0.f, sr0p=0.f, tr0p=0.f;
      #pragma unroll
      for (int k=0;k<2;++k){
        int st = 2*r0b+k+1;
        const float* bymk = k ? by_[0] : bym0_;
        float zc[4], zu[4], zd[4], tv[4];
        #pragma unroll
        for (int j=0;j<4;++j) zc[j] = r_[k][j] - alpha*v_[k][j];
        LD4(zu, &tile[st-1][c4o]);
        LD4(zd, &tile[st+1][c4o]);
        float zl = __shfl_up(zc[3], 1);
        float zr = __shfl_down(zc[0], 1);
        if (lane==0)  zl = (c4o==0)   ? zc[0] : tile[st][c4o-1];
        if (lane==63) zr = (c4o==508) ? zc[3] : tile[st][c4o+4];
        stencil_reg(zc, zl, zr, zu, zd, ax_[k], axl_[k], by_[k], bymk, tv);
        #pragma unroll
        for (int j=0;j<4;++j){
          tsp  += tv[j]*zc[j];
          ttp  += tv[j]*tv[j];
          sr0p += zc[j]*r0_[k][j];
          tr0p += tv[j]*r0_[k][j];
        }
        if (k==0){ CP4(t0s, tv); }
        else     { CP4(t1s, tv); }
      }
      if (r0b==0) hstore4(THq, row0o, t0s);
      if (r0b==3) hstore4(THq, row7o, t1s);
      red[0]=ssp; red[1]=tsp; red[2]=ttp; red[3]=sr0p; red[4]=tr0p;
      ++ep; phase_sync(Aq,Bq,img,sub,ep, red, 5);
    }
    float ss=red[0], ts=red[1], tt=red[2], s_r0=red[3], t_r0=red[4];
    float snorm = sqrtf(ss);

    if (snorm <= THR){
      // ---- c3: x += alpha*p; loop exits on next check ----
      #pragma unroll
      for (int k=0;k<2;++k)
        #pragma unroll
        for (int j=0;j<4;++j) x_[k][j] += alpha*p_[k][j];
      rabs = snorm; kcnt++; c4p = false;
      continue;
    }

    // ---- c4 (local): x += alpha*p + omega*s; r = s - omega*t ----
    omega = ts/tt;
    #pragma unroll
    for (int k=0;k<2;++k){
      int st = 2*r0b+k+1;
      const float* bymk = k ? by_[0] : bym0_;
      float zc[4], zu[4], zd[4], tv[4];
      #pragma unroll
      for (int j=0;j<4;++j) zc[j] = r_[k][j] - alpha*v_[k][j];
      LD4(zu, &tile[st-1][c4o]);
      LD4(zd, &tile[st+1][c4o]);
      float zl = __shfl_up(zc[3], 1);
      float zr = __shfl_down(zc[0], 1);
      if (lane==0)  zl = (c4o==0)   ? zc[0] : tile[st][c4o-1];
      if (lane==63) zr = (c4o==508) ? zc[3] : tile[st][c4o+4];
      stencil_reg(zc, zl, zr, zu, zd, ax_[k], axl_[k], by_[k], bymk, tv);
      #pragma unroll
      for (int j=0;j<4;++j){
        x_[k][j] = x_[k][j] + alpha*p_[k][j] + omega*zc[j];
        r_[k][j] = zc[j] - omega*tv[j];
      }
    }
    // halo mirror updates (r,x at rows -1 / 8)
    if (r0b==0){
      float th[4];
      if (sub==0){ CP4(th, t0s); } else hload4(THq, rowm1o, th);
      #pragma unroll
      for (int j=0;j<4;++j){
        float sh = rh_[j] - alpha*vh_[j];
        xh_[j] = xh_[j] + alpha*ph_[j] + omega*sh;
        rh_[j] = sh - omega*th[j];
      }
    }
    if (r0b==3){
      float th[4];
      if (sub==IPB-1){ CP4(th, t1s); } else hload4(THq, row8o, th);
      #pragma unroll
      for (int j=0;j<4;++j){
        float sh = rh_[j] - alpha*vh_[j];
        xh_[j] = xh_[j] + alpha*ph_[j] + omega*sh;
        rh_[j] = sh - omega*th[j];
      }
    }
    float rr0n = s_r0 - omega*t_r0;
    rabs = sqrtf(fmaxf(ss - 2.f*omega*ts + omega*omega*tt, 0.f));
    beta = alpha/omega*(rr0n/rr0);
    rr0 = rr0n; kcnt++;
    c4p = true;
  }

  // ---- pack: out[img][i][j]: border=c, interior = x[j-1][i-1] ----
  __syncthreads();
  float* lp = &tile[0][0];                  // reused as [8][516]
  #pragma unroll
  for (int k=0;k<2;++k){
    int ri = 2*r0b + k;
    ST4(lp + ri*516 + c4o, x_[k]);
  }
  float* outb = outg + (size_t)img*PADS*PADS;
  if (sub == 0){
    for (int e = tid; e < 2052; e += NT){
      int i, j;
      if (e < 514)      { i=0;        j=e;      }
      else if (e < 1028){ i=513;      j=e-514;  }
      else if (e < 1540){ i=e-1028+1; j=0;      }
      else              { i=e-1540+1; j=513;    }
      outb[i*PADS+j] = c;
    }
  }
  __syncthreads();
  {
    int qq = tid & 7, xb = tid >> 3;        // 8 rows x 64 col-groups
    #pragma unroll
    for (int ps=0; ps<8; ++ps){
      int xc = ps*64 + xb;
      outb[(size_t)(xc+1)*PADS + (y0+1+qq)] = lp[qq*516 + xc];
    }
  }
}

} // namespace

extern "C" void kernel_launch(void* const* d_in, const int* in_sizes, int n_in,
                              void* d_out, int out_size, void* d_ws, size_t ws_size,
                              hipStream_t stream){
  const float* V  = (const float*)d_in[0];
  const float* M1 = (const float*)d_in[1];
  const float* M2 = (const float*)d_in[2];
  const int*   km = (const int*)d_in[3];
  float* ws  = (float*)d_ws;
  float* out = (float*)d_out;

  size_t need = (size_t)NPLH*NSF*sizeof(float) + (A_QW + B_QW)*sizeof(ull);
  if (ws_size < need) return;

  // zero the slot/broadcast region each call (graph-capturable)
  hipMemsetAsync((char*)d_ws + (size_t)NPLH*NSF*sizeof(float),
                 0, (A_QW + B_QW)*sizeof(ull), stream);

  solve<<<dim3(NB), dim3(NT), 0, stream>>>(V, M1, M2, km, out, ws);
}

// Round 11
// 530.524 us; speedup vs baseline: 1.0018x; 1.0018x over previous
//
#include <hip/hip_runtime.h>
#include <math.h>

// BiCGStab, 8 independent 512x512 images, single persistent kernel.
// 256 blocks x 1024 threads (16 waves). Residency is STRUCTURAL: a
// 1024-thread flat workgroup forces VGPR<=128 (4 waves/SIMD x 128 = pool),
// and 1 block/CU always fits (any VGPR<=128, LDS 37KB) -> grid 256 = #CUs
// is unconditionally co-resident. No occupancy hints.
// Block = 16 contiguous rows; thread = 2 rows x 4 cols (~105 live VGPRs,
// no spills). Fields (x,p,r,r0,v) + coefficients in registers; s in LDS;
// t recomputed. TWO syncs per iteration (c4 reductions folded into P2).
// Sync: fence-free aggregator protocol (round-8 validated). Blocks post
// partials (relaxed agent atomics, value|epoch packed); block sub==0 of each
// image polls+reduces them once, publishes sums into ONE 64B line; the other
// 31 blocks poll that single line. __syncthreads drains vmcnt before posts.

namespace {

typedef unsigned long long ull;

constexpr int NIMG = 8;
constexpr int NSd  = 512;
constexpr int S    = NSd*NSd;
constexpr int NSF  = NIMG*S;
constexpr int PADS = 514;
constexpr int NB   = 256;
constexpr int IPB  = 32;     // blocks per image
constexpr int NT   = 1024;
constexpr float EPSF = 1e-9f;
constexpr float THR  = 1e-9f * 262144.0f;
constexpr float RX_=50.f, RY_=50.f, RXX_=100.f, RYY_=100.f;
constexpr float BOO0 = 1.f + 2.f*(RXX_+RYY_);

enum { P_PH=0, P_VH, P_TH, NPLH };                 // halo planes (atomic qwords)
constexpr size_t A_QW = (size_t)NIMG*2*8*32;       // 4096 qwords (32 KB)
constexpr size_t B_QW = (size_t)NIMG*2*8;          // 128 qwords (1 KB)

__device__ __forceinline__ int cl(int i){ return i<0?0:(i>NSd-1?NSd-1:i); }

#define LD4(d, p) { float4 _t4 = *reinterpret_cast<const float4*>(p); \
  (d)[0]=_t4.x; (d)[1]=_t4.y; (d)[2]=_t4.z; (d)[3]=_t4.w; }
#define ST4(p, s) { *reinterpret_cast<float4*>(p) = \
  make_float4((s)[0],(s)[1],(s)[2],(s)[3]); }
#define CP4(d, s) { (d)[0]=(s)[0]; (d)[1]=(s)[1]; (d)[2]=(s)[2]; (d)[3]=(s)[3]; }

// ---- coherent halo row I/O (relaxed agent atomics, 2 floats per qword) ----
__device__ __forceinline__ void hstore4(ull* pq, int off_f, const float s[4]){
  size_t q = (size_t)off_f >> 1;
  ull u0 = ((ull)__float_as_uint(s[1])<<32) | (ull)__float_as_uint(s[0]);
  ull u1 = ((ull)__float_as_uint(s[3])<<32) | (ull)__float_as_uint(s[2]);
  __hip_atomic_store(pq+q,   u0, __ATOMIC_RELAXED, __HIP_MEMORY_SCOPE_AGENT);
  __hip_atomic_store(pq+q+1, u1, __ATOMIC_RELAXED, __HIP_MEMORY_SCOPE_AGENT);
}
__device__ __forceinline__ void hload4(const ull* pq, int off_f, float d[4]){
  size_t q = (size_t)off_f >> 1;
  ull u0 = __hip_atomic_load(pq+q,   __ATOMIC_RELAXED, __HIP_MEMORY_SCOPE_AGENT);
  ull u1 = __hip_atomic_load(pq+q+1, __ATOMIC_RELAXED, __HIP_MEMORY_SCOPE_AGENT);
  d[0]=__uint_as_float((unsigned)u0); d[1]=__uint_as_float((unsigned)(u0>>32));
  d[2]=__uint_as_float((unsigned)u1); d[3]=__uint_as_float((unsigned)(u1>>32));
}

// ---- aggregator phase sync: post -> (sub0 reduces+publishes) -> broadcast ----
__device__ __forceinline__ void phase_sync(ull* Aq, ull* Bq, int img, int sub,
    unsigned ep, float* v, int n){
  __shared__ float acc[16][5];
  __shared__ float bc[5];
  const int tid = threadIdx.x, w = tid>>6, lane = tid&63;
  #pragma unroll
  for (int i=0;i<5;++i){
    if (i<n){
      float a = v[i];
      #pragma unroll
      for (int o=32;o;o>>=1) a += __shfl_xor(a,o);
      if (lane==0) acc[w][i] = a;
    }
  }
  __syncthreads();   // acc ready; drains vmcnt (halo stores globally visible)
  const int par = ep & 1;
  ull* Ab = Aq + ((size_t)(img*2+par)*8)*32;   // [sum][32] qwords, 256B rows
  ull* Bb = Bq + ((size_t)(img*2+par))*8;      // one 64B line
  if (sub == 0){
    if (w < n){
      float own = 0.f;
      #pragma unroll
      for (int i=0;i<16;++i) own += acc[i][w];
      ull x = 0; const bool me = (lane>=1 && lane<32);
      for(;;){
        bool ok = true;
        if (me){
          x = __hip_atomic_load(Ab + w*32 + lane, __ATOMIC_RELAXED, __HIP_MEMORY_SCOPE_AGENT);
          ok = ((unsigned)x == ep);
        }
        if (__all(ok)) break;
        __builtin_amdgcn_s_sleep(2);
      }
      float a = me ? __uint_as_float((unsigned)(x>>32)) : ((lane==0)? own : 0.f);
      #pragma unroll
      for (int o=16;o;o>>=1) a += __shfl_xor(a,o);   // lanes 0..31
      if (lane==0){
        bc[w] = a;
        ull pk = ((ull)__float_as_uint(a)<<32) | (ull)ep;
        __hip_atomic_store(Bb + w, pk, __ATOMIC_RELAXED, __HIP_MEMORY_SCOPE_AGENT);
      }
    }
  } else {
    if (tid < n){
      float t = 0.f;
      #pragma unroll
      for (int i=0;i<16;++i) t += acc[i][tid];
      ull pk = ((ull)__float_as_uint(t)<<32) | (ull)ep;
      __hip_atomic_store(Ab + tid*32 + sub, pk, __ATOMIC_RELAXED, __HIP_MEMORY_SCOPE_AGENT);
    }
    if (w == 0){
      ull x = 0; const bool me = (lane < n);
      for(;;){
        bool ok = true;
        if (me){
          x = __hip_atomic_load(Bb + lane, __ATOMIC_RELAXED, __HIP_MEMORY_SCOPE_AGENT);
          ok = ((unsigned)x == ep);
        }
        if (__all(ok)) break;
        __builtin_amdgcn_s_sleep(2);
      }
      if (me) bc[lane] = __uint_as_float((unsigned)(x>>32));
    }
  }
  __syncthreads();
  #pragma unroll
  for (int i=0;i<5;++i) if (i<n) v[i] = bc[i];
}

// 5-point stencil, center strip from registers; reference summation order
__device__ __forceinline__ void stencil_reg(const float zc[4], float zl, float zr,
    const float zu[4], const float zd[4],
    const float ax[4], float axl, const float by[4], const float bym[4],
    float out[4]){
  #pragma unroll
  for (int j=0;j<4;++j){
    float axm = j ? ax[j-1] : axl;
    float zxm = j ? zc[j-1] : zl;
    float zxp = (j<3) ? zc[j+1] : zr;
    float boo = BOO0 + ax[j] - axm + by[j] - bym[j];
    out[j] = boo*zc[j] + (-RXX_-axm)*zxm + (-RYY_-bym[j])*zu[j]
           + (-RYY_+by[j])*zd[j] + (-RXX_+ax[j])*zxp;
  }
}

__global__ void __launch_bounds__(NT)
solve(const float* __restrict__ Vg,
    const float* __restrict__ M1g, const float* __restrict__ M2g,
    const int* __restrict__ kmp, float* __restrict__ outg, float* __restrict__ ws){
  __shared__ float tile[18][NSd];        // 36864 B; reused as [16][516] at pack
  const int tid = threadIdx.x, blk = blockIdx.x;
  const int img = blk & 7, sub = blk >> 3;       // 32 blocks per image
  const int y0 = sub*16, bS = img*S;
  const int cg = tid & 127, r0b = tid >> 7, c4o = cg*4;   // r0b in [0,8)
  const int lane = tid & 63;
  ull* PHq = (ull*)(ws + (size_t)P_PH*NSF);
  ull* VHq = (ull*)(ws + (size_t)P_VH*NSF);
  ull* THq = (ull*)(ws + (size_t)P_TH*NSF);
  ull* Aq  = (ull*)(ws + (size_t)NPLH*NSF);
  ull* Bq  = Aq + A_QW;
  unsigned ep = 0;
  const int kmax = kmp[0];
  const int row0o  = bS + (y0<<9) + c4o;        // row y0    (published by r0b==0)
  const int row15o = bS + ((y0+15)<<9) + c4o;   // row y0+15 (published by r0b==7)
  const int rowm1o = bS + ((y0-1)<<9) + c4o;    // valid only if sub>0
  const int row16o = bS + ((y0+16)<<9) + c4o;   // valid only if sub<31
  float red[5];

  // ---- setup: coefficients into registers (rows y0 + 2*r0b + k, k=0,1) ----
  float ax_[2][4], axl_[2], by_[2][4], bym0_[4];
  float msum = 0.f;
  #pragma unroll
  for (int k=0;k<2;++k){
    int fy = y0 + 2*r0b + k, ro = bS + (fy<<9);
    float vc[4], vd[4], m1[4], m2[4];
    LD4(vc, Vg+ro+c4o);
    float vr  = Vg[ro + (c4o<508 ? c4o+4 : 511)];
    float vl  = c4o ? Vg[ro+c4o-1]  : vc[0];
    float m1l = c4o ? M1g[ro+c4o-1] : 0.f;
    LD4(vd, Vg + bS + (cl(fy+1)<<9) + c4o);
    LD4(m1, M1g+ro+c4o);
    LD4(m2, M2g+ro+c4o);
    #pragma unroll
    for (int j=0;j<4;++j){
      float vn = (j<3) ? vc[j+1] : vr;
      ax_[k][j] = RX_*((vn-vc[j])/(0.5f*(vn+vc[j])))*m1[j];
      by_[k][j] = RY_*((vd[j]-vc[j])/(0.5f*(vd[j]+vc[j])))*m2[j];
      msum += vc[j];
    }
    axl_[k] = c4o ? RX_*((vc[0]-vl)/(0.5f*(vc[0]+vl)))*m1l : 0.f;
    if (k==0){
      if (fy > 0){
        float vu[4], m2u[4];
        LD4(vu, Vg + bS + ((fy-1)<<9) + c4o);
        LD4(m2u, M2g + bS + ((fy-1)<<9) + c4o);
        #pragma unroll
        for (int j=0;j<4;++j)
          bym0_[j] = RY_*((vc[j]-vu[j])/(0.5f*(vc[j]+vu[j])))*m2u[j];
      } else {
        bym0_[0]=0.f; bym0_[1]=0.f; bym0_[2]=0.f; bym0_[3]=0.f;
      }
    }
  }
  red[0]=msum;
  ++ep; phase_sync(Aq,Bq,img,sub,ep, red, 1);
  const float c = red[0]*(1.0f/262144.0f);

  // ---- init: x=c, p=r=r0 = b - A(c) = -2c(ax-axm+by-bym) ----
  float x_[2][4], p_[2][4], r_[2][4], r0_[2][4], v_[2][4];
  float ph_[4], rh_[4], xh_[4], vh_[4];   // halo-row mirrors (r0b 0/7)
  {
    float pa = 0.f;
    #pragma unroll
    for (int k=0;k<2;++k){
      const float* bymk = k ? by_[0] : bym0_;
      #pragma unroll
      for (int j=0;j<4;++j){
        float axm = j ? ax_[k][j-1] : axl_[k];
        float pn = -2.f*c*(ax_[k][j]-axm + by_[k][j]-bymk[j]);
        x_[k][j]=c; p_[k][j]=pn; r_[k][j]=pn; r0_[k][j]=pn; v_[k][j]=0.f;
        pa += pn*pn;
      }
    }
    #pragma unroll
    for (int j=0;j<4;++j){ xh_[j]=c; ph_[j]=0.f; rh_[j]=0.f; vh_[j]=0.f; }
    if (r0b==0) hstore4(PHq, row0o, p_[0]);
    if (r0b==7) hstore4(PHq, row15o, p_[1]);
    red[0]=pa;
    ++ep; phase_sync(Aq,Bq,img,sub,ep, red, 1);
  }
  float rr0 = red[0];
  float r0abs = sqrtf(rr0), rabs = r0abs;
  int kcnt = 0;
  bool c4p = false;
  float alpha=0.f, omega=0.f, beta=0.f;

  for (int it=0; it<kmax; ++it){
    if (!((kcnt < kmax) && (rabs > THR))) break;

    // ================= P1: p-update; v = A(p); <v,r0>, <v,v> =================
    if (c4p){
      #pragma unroll
      for (int k=0;k<2;++k)
        #pragma unroll
        for (int j=0;j<4;++j)
          p_[k][j] = r_[k][j] + beta*(p_[k][j]-omega*v_[k][j]);
      if (r0b==0 || r0b==7){
        #pragma unroll
        for (int j=0;j<4;++j) ph_[j] = rh_[j] + beta*(ph_[j]-omega*vh_[j]);
      }
    } else {
      // after init/restart: r==p; refresh mirrors from PH (or own row)
      if (r0b==0){
        if (sub==0){ CP4(ph_, p_[0]); } else hload4(PHq, rowm1o, ph_);
        CP4(rh_, ph_);
      }
      if (r0b==7){
        if (sub==IPB-1){ CP4(ph_, p_[1]); } else hload4(PHq, row16o, ph_);
        CP4(rh_, ph_);
      }
    }
    #pragma unroll
    for (int k=0;k<2;++k){ ST4(&tile[2*r0b+k+1][c4o], p_[k]); }
    if (r0b==0) ST4(&tile[0][c4o], ph_);
    if (r0b==7) ST4(&tile[17][c4o], ph_);
    __syncthreads();
    {
      float s1=0.f, s2=0.f;
      #pragma unroll
      for (int k=0;k<2;++k){
        int st = 2*r0b+k+1;
        const float* bymk = k ? by_[0] : bym0_;
        float zu[4], zd[4], ov[4];
        LD4(zu, &tile[st-1][c4o]);
        LD4(zd, &tile[st+1][c4o]);
        float zl = __shfl_up(p_[k][3], 1);
        float zr = __shfl_down(p_[k][0], 1);
        if (lane==0)  zl = (c4o==0)   ? p_[k][0] : tile[st][c4o-1];
        if (lane==63) zr = (c4o==508) ? p_[k][3] : tile[st][c4o+4];
        stencil_reg(p_[k], zl, zr, zu, zd, ax_[k], axl_[k], by_[k], bymk, ov);
        #pragma unroll
        for (int j=0;j<4;++j){
          v_[k][j]=ov[j]; s1 += ov[j]*r0_[k][j]; s2 += ov[j]*ov[j];
        }
      }
      if (r0b==0) hstore4(VHq, row0o, v_[0]);
      if (r0b==7) hstore4(VHq, row15o, v_[1]);
      red[0]=s1; red[1]=s2;
      ++ep; phase_sync(Aq,Bq,img,sub,ep, red, 2);
    }
    float sig = red[0], vabs = sqrtf(red[1]);

    if (sig <= EPSF*vabs*r0abs){
      // ---- restart: p = r = r0 = b - A(x) ----
      #pragma unroll
      for (int k=0;k<2;++k){ ST4(&tile[2*r0b+k+1][c4o], x_[k]); }
      if (r0b==0) ST4(&tile[0][c4o], xh_);
      if (r0b==7) ST4(&tile[17][c4o], xh_);
      __syncthreads();
      float pa = 0.f;
      #pragma unroll
      for (int k=0;k<2;++k){
        int st = 2*r0b+k+1;
        const float* bymk = k ? by_[0] : bym0_;
        float zu[4], zd[4], av[4];
        LD4(zu, &tile[st-1][c4o]);
        LD4(zd, &tile[st+1][c4o]);
        float zl = __shfl_up(x_[k][3], 1);
        float zr = __shfl_down(x_[k][0], 1);
        if (lane==0)  zl = (c4o==0)   ? x_[k][0] : tile[st][c4o-1];
        if (lane==63) zr = (c4o==508) ? x_[k][3] : tile[st][c4o+4];
        stencil_reg(x_[k], zl, zr, zu, zd, ax_[k], axl_[k], by_[k], bymk, av);
        #pragma unroll
        for (int j=0;j<4;++j){
          float pn = c - av[j];
          p_[k][j]=pn; r_[k][j]=pn; r0_[k][j]=pn;
          pa += pn*pn;
        }
      }
      if (r0b==0) hstore4(PHq, row0o, p_[0]);
      if (r0b==7) hstore4(PHq, row15o, p_[1]);
      red[0]=pa;
      ++ep; phase_sync(Aq,Bq,img,sub,ep, red, 1);
      rr0 = red[0]; r0abs = sqrtf(rr0); rabs = r0abs; kcnt++;
      c4p = false;
      continue;
    }

    // ================= P2: s; t=A(s); 5 sums (c4 folded in) =================
    alpha = rr0 / sig;
    if (r0b==0){
      if (sub==0){ CP4(vh_, v_[0]); } else hload4(VHq, rowm1o, vh_);
    }
    if (r0b==7){
      if (sub==IPB-1){ CP4(vh_, v_[1]); } else hload4(VHq, row16o, vh_);
    }
    float t0s[4], t1s[4];
    {
      float ssp = 0.f;
      #pragma unroll
      for (int k=0;k<2;++k){
        float sv[4];
        #pragma unroll
        for (int j=0;j<4;++j){
          sv[j] = r_[k][j] - alpha*v_[k][j];
          ssp += sv[j]*sv[j];
        }
        ST4(&tile[2*r0b+k+1][c4o], sv);
      }
      if (r0b==0){
        float sh[4];
        #pragma unroll
        for (int j=0;j<4;++j) sh[j] = rh_[j] - alpha*vh_[j];
        ST4(&tile[0][c4o], sh);
      }
      if (r0b==7){
        float sh[4];
        #pragma unroll
        for (int j=0;j<4;++j) sh[j] = rh_[j] - alpha*vh_[j];
        ST4(&tile[17][c4o], sh);
      }
      __syncthreads();
      float tsp=0.f, ttp=0.f, sr0p=0.f, tr0p=0.f;
      #pragma unroll
      for (int k=0;k<2;++k){
        int st = 2*r0b+k+1;
        const float* bymk = k ? by_[0] : bym0_;
        float zc[4], zu[4], zd[4], tv[4];
        #pragma unroll
        for (int j=0;j<4;++j) zc[j] = r_[k][j] - alpha*v_[k][j];
        LD4(zu, &tile[st-1][c4o]);
        LD4(zd, &tile[st+1][c4o]);
        float zl = __shfl_up(zc[3], 1);
        float zr = __shfl_down(zc[0], 1);
        if (lane==0)  zl = (c4o==0)   ? zc[0] : tile[st][c4o-1];
        if (lane==63) zr = (c4o==508) ? zc[3] : tile[st][c4o+4];
        stencil_reg(zc, zl, zr, zu, zd, ax_[k], axl_[k], by_[k], bymk, tv);
        #pragma unroll
        for (int j=0;j<4;++j){
          tsp  += tv[j]*zc[j];
          ttp  += tv[j]*tv[j];
          sr0p += zc[j]*r0_[k][j];
          tr0p += tv[j]*r0_[k][j];
        }
        if (k==0){ CP4(t0s, tv); }
        else     { CP4(t1s, tv); }
      }
      if (r0b==0) hstore4(THq, row0o, t0s);
      if (r0b==7) hstore4(THq, row15o, t1s);
      red[0]=ssp; red[1]=tsp; red[2]=ttp; red[3]=sr0p; red[4]=tr0p;
      ++ep; phase_sync(Aq,Bq,img,sub,ep, red, 5);
    }
    float ss=red[0], ts=red[1], tt=red[2], s_r0=red[3], t_r0=red[4];
    float snorm = sqrtf(ss);

    if (snorm <= THR){
      // ---- c3: x += alpha*p; loop exits on next check ----
      #pragma unroll
      for (int k=0;k<2;++k)
        #pragma unroll
        for (int j=0;j<4;++j) x_[k][j] += alpha*p_[k][j];
      rabs = snorm; kcnt++; c4p = false;
      continue;
    }

    // ---- c4 (local): x += alpha*p + omega*s; r = s - omega*t ----
    omega = ts/tt;
    #pragma unroll
    for (int k=0;k<2;++k){
      int st = 2*r0b+k+1;
      const float* bymk = k ? by_[0] : bym0_;
      float zc[4], zu[4], zd[4], tv[4];
      #pragma unroll
      for (int j=0;j<4;++j) zc[j] = r_[k][j] - alpha*v_[k][j];
      LD4(zu, &tile[st-1][c4o]);
      LD4(zd, &tile[st+1][c4o]);
      float zl = __shfl_up(zc[3], 1);
      float zr = __shfl_down(zc[0], 1);
      if (lane==0)  zl = (c4o==0)   ? zc[0] : tile[st][c4o-1];
      if (lane==63) zr = (c4o==508) ? zc[3] : tile[st][c4o+4];
      stencil_reg(zc, zl, zr, zu, zd, ax_[k], axl_[k], by_[k], bymk, tv);
      #pragma unroll
      for (int j=0;j<4;++j){
        x_[k][j] = x_[k][j] + alpha*p_[k][j] + omega*zc[j];
        r_[k][j] = zc[j] - omega*tv[j];
      }
    }
    // halo mirror updates (r,x at rows -1 / 16)
    if (r0b==0){
      float th[4];
      if (sub==0){ CP4(th, t0s); } else hload4(THq, rowm1o, th);
      #pragma unroll
      for (int j=0;j<4;++j){
        float sh = rh_[j] - alpha*vh_[j];
        xh_[j] = xh_[j] + alpha*ph_[j] + omega*sh;
        rh_[j] = sh - omega*th[j];
      }
    }
    if (r0b==7){
      float th[4];
      if (sub==IPB-1){ CP4(th, t1s); } else hload4(THq, row16o, th);
      #pragma unroll
      for (int j=0;j<4;++j){
        float sh = rh_[j] - alpha*vh_[j];
        xh_[j] = xh_[j] + alpha*ph_[j] + omega*sh;
        rh_[j] = sh - omega*th[j];
      }
    }
    float rr0n = s_r0 - omega*t_r0;
    rabs = sqrtf(fmaxf(ss - 2.f*omega*ts + omega*omega*tt, 0.f));
    beta = alpha/omega*(rr0n/rr0);
    rr0 = rr0n; kcnt++;
    c4p = true;
  }

  // ---- pack: out[img][i][j]: border=c, interior = x[j-1][i-1] ----
  __syncthreads();
  float* lp = &tile[0][0];                  // reused as [16][516]
  #pragma unroll
  for (int k=0;k<2;++k){
    int ri = 2*r0b + k;
    ST4(lp + ri*516 + c4o, x_[k]);
  }
  float* outb = outg + (size_t)img*PADS*PADS;
  if (sub == 0){
    for (int e = tid; e < 2052; e += NT){
      int i, j;
      if (e < 514)      { i=0;        j=e;      }
      else if (e < 1028){ i=513;      j=e-514;  }
      else if (e < 1540){ i=e-1028+1; j=0;      }
      else              { i=e-1540+1; j=513;    }
      outb[i*PADS+j] = c;
    }
  }
  __syncthreads();
  {
    int qq = tid & 15, xb = tid >> 4;       // 16 rows x 64 col-groups
    #pragma unroll
    for (int ps=0; ps<8; ++ps){
      int xc = ps*64 + xb;
      outb[(size_t)(xc+1)*PADS + (y0+1+qq)] = lp[qq*516 + xc];
    }
  }
}

} // namespace

extern "C" void kernel_launch(void* const* d_in, const int* in_sizes, int n_in,
                              void* d_out, int out_size, void* d_ws, size_t ws_size,
                              hipStream_t stream){
  const float* V  = (const float*)d_in[0];
  const float* M1 = (const float*)d_in[1];
  const float* M2 = (const float*)d_in[2];
  const int*   km = (const int*)d_in[3];
  float* ws  = (float*)d_ws;
  float* out = (float*)d_out;

  size_t need = (size_t)NPLH*NSF*sizeof(float) + (A_QW + B_QW)*sizeof(ull);
  if (ws_size < need) return;

  // zero the slot/broadcast region each call (graph-capturable)
  hipMemsetAsync((char*)d_ws + (size_t)NPLH*NSF*sizeof(float),
                 0, (A_QW + B_QW)*sizeof(ull), stream);

  solve<<<dim3(NB), dim3(NT), 0, stream>>>(V, M1, M2, km, out, ws);
}

// Round 12
// 315.170 us; speedup vs baseline: 1.6863x; 1.6833x over previous
//
#include <hip/hip_runtime.h>
#include <math.h>

// BiCGStab, 8 independent 512x512 images, single persistent kernel.
// 256 blocks x 512 threads. Occupancy pinned via LDS: 84KB/block => max
// 1 workgroup/CU => register budget rises to 256 VGPR (8 waves = 2/SIMD)
// => round-8 live set fits with ZERO spills. Residency structural:
// grid 256 = #CUs, 1 WG/CU always schedulable => spin sync deadlock-free.
// Block = 16 contiguous rows; thread = 4 rows x 4 cols.
// Fields (x,p,r,v) + coefficients in registers; r0 in persistent LDS;
// s in LDS tile; t recomputed. TWO syncs/iteration (c4 dots folded into P2).
// Sync: fence-free aggregator protocol (round-8 validated, 408us).

namespace {

typedef unsigned long long ull;

constexpr int NIMG = 8;
constexpr int NSd  = 512;
constexpr int S    = NSd*NSd;
constexpr int NSF  = NIMG*S;
constexpr int PADS = 514;
constexpr int NB   = 256;
constexpr int IPB  = 32;     // blocks per image
constexpr int NT   = 512;
constexpr float EPSF = 1e-9f;
constexpr float THR  = 1e-9f * 262144.0f;
constexpr float RX_=50.f, RY_=50.f, RXX_=100.f, RYY_=100.f;
constexpr float BOO0 = 1.f + 2.f*(RXX_+RYY_);

enum { P_PH=0, P_VH, P_TH, NPLH };                 // halo planes (atomic qwords)
constexpr size_t A_QW = (size_t)NIMG*2*8*32;       // 4096 qwords (32 KB)
constexpr size_t B_QW = (size_t)NIMG*2*8;          // 128 qwords (1 KB)

__device__ __forceinline__ int cl(int i){ return i<0?0:(i>NSd-1?NSd-1:i); }

#define LD4(d, p) { float4 _t4 = *reinterpret_cast<const float4*>(p); \
  (d)[0]=_t4.x; (d)[1]=_t4.y; (d)[2]=_t4.z; (d)[3]=_t4.w; }
#define ST4(p, s) { *reinterpret_cast<float4*>(p) = \
  make_float4((s)[0],(s)[1],(s)[2],(s)[3]); }
#define CP4(d, s) { (d)[0]=(s)[0]; (d)[1]=(s)[1]; (d)[2]=(s)[2]; (d)[3]=(s)[3]; }

// ---- coherent halo row I/O (relaxed agent atomics, 2 floats per qword) ----
__device__ __forceinline__ void hstore4(ull* pq, int off_f, const float s[4]){
  size_t q = (size_t)off_f >> 1;
  ull u0 = ((ull)__float_as_uint(s[1])<<32) | (ull)__float_as_uint(s[0]);
  ull u1 = ((ull)__float_as_uint(s[3])<<32) | (ull)__float_as_uint(s[2]);
  __hip_atomic_store(pq+q,   u0, __ATOMIC_RELAXED, __HIP_MEMORY_SCOPE_AGENT);
  __hip_atomic_store(pq+q+1, u1, __ATOMIC_RELAXED, __HIP_MEMORY_SCOPE_AGENT);
}
__device__ __forceinline__ void hload4(const ull* pq, int off_f, float d[4]){
  size_t q = (size_t)off_f >> 1;
  ull u0 = __hip_atomic_load(pq+q,   __ATOMIC_RELAXED, __HIP_MEMORY_SCOPE_AGENT);
  ull u1 = __hip_atomic_load(pq+q+1, __ATOMIC_RELAXED, __HIP_MEMORY_SCOPE_AGENT);
  d[0]=__uint_as_float((unsigned)u0); d[1]=__uint_as_float((unsigned)(u0>>32));
  d[2]=__uint_as_float((unsigned)u1); d[3]=__uint_as_float((unsigned)(u1>>32));
}

// ---- aggregator phase sync: post -> (sub0 reduces+publishes) -> broadcast ----
__device__ __forceinline__ void phase_sync(ull* Aq, ull* Bq, int img, int sub,
    unsigned ep, float* v, int n){
  __shared__ float acc[8][5];
  __shared__ float bc[5];
  const int tid = threadIdx.x, w = tid>>6, lane = tid&63;
  #pragma unroll
  for (int i=0;i<5;++i){
    if (i<n){
      float a = v[i];
      #pragma unroll
      for (int o=32;o;o>>=1) a += __shfl_xor(a,o);
      if (lane==0) acc[w][i] = a;
    }
  }
  __syncthreads();   // acc ready; drains vmcnt (halo stores globally visible)
  const int par = ep & 1;
  ull* Ab = Aq + ((size_t)(img*2+par)*8)*32;   // [sum][32] qwords, 256B rows
  ull* Bb = Bq + ((size_t)(img*2+par))*8;      // one 64B line
  if (sub == 0){
    if (w < n){
      float own = 0.f;
      #pragma unroll
      for (int i=0;i<8;++i) own += acc[i][w];
      ull x = 0; const bool me = (lane>=1 && lane<32);
      for(;;){
        bool ok = true;
        if (me){
          x = __hip_atomic_load(Ab + w*32 + lane, __ATOMIC_RELAXED, __HIP_MEMORY_SCOPE_AGENT);
          ok = ((unsigned)x == ep);
        }
        if (__all(ok)) break;
        __builtin_amdgcn_s_sleep(2);
      }
      float a = me ? __uint_as_float((unsigned)(x>>32)) : ((lane==0)? own : 0.f);
      #pragma unroll
      for (int o=16;o;o>>=1) a += __shfl_xor(a,o);   // lanes 0..31
      if (lane==0){
        bc[w] = a;
        ull pk = ((ull)__float_as_uint(a)<<32) | (ull)ep;
        __hip_atomic_store(Bb + w, pk, __ATOMIC_RELAXED, __HIP_MEMORY_SCOPE_AGENT);
      }
    }
  } else {
    if (tid < n){
      float t = 0.f;
      #pragma unroll
      for (int i=0;i<8;++i) t += acc[i][tid];
      ull pk = ((ull)__float_as_uint(t)<<32) | (ull)ep;
      __hip_atomic_store(Ab + tid*32 + sub, pk, __ATOMIC_RELAXED, __HIP_MEMORY_SCOPE_AGENT);
    }
    if (w == 0){
      ull x = 0; const bool me = (lane < n);
      for(;;){
        bool ok = true;
        if (me){
          x = __hip_atomic_load(Bb + lane, __ATOMIC_RELAXED, __HIP_MEMORY_SCOPE_AGENT);
          ok = ((unsigned)x == ep);
        }
        if (__all(ok)) break;
        __builtin_amdgcn_s_sleep(2);
      }
      if (me) bc[lane] = __uint_as_float((unsigned)(x>>32));
    }
  }
  __syncthreads();
  #pragma unroll
  for (int i=0;i<5;++i) if (i<n) v[i] = bc[i];
}

// 5-point stencil, center strip from registers; reference summation order
__device__ __forceinline__ void stencil_reg(const float zc[4], float zl, float zr,
    const float zu[4], const float zd[4],
    const float ax[4], float axl, const float by[4], const float bym[4],
    float out[4]){
  #pragma unroll
  for (int j=0;j<4;++j){
    float axm = j ? ax[j-1] : axl;
    float zxm = j ? zc[j-1] : zl;
    float zxp = (j<3) ? zc[j+1] : zr;
    float boo = BOO0 + ax[j] - axm + by[j] - bym[j];
    out[j] = boo*zc[j] + (-RXX_-axm)*zxm + (-RYY_-bym[j])*zu[j]
           + (-RYY_+by[j])*zd[j] + (-RXX_+ax[j])*zxp;
  }
}

__global__ void __launch_bounds__(NT)
solve(const float* __restrict__ Vg,
    const float* __restrict__ M1g, const float* __restrict__ M2g,
    const int* __restrict__ kmp, float* __restrict__ outg, float* __restrict__ ws){
  // 25*512*4 = 51200 B (rows 0..17 used as halo tile; full size forces LDS
  // occupancy) + r0 plane 16*512*4 = 32768 B => 83968 B > 80KB => 1 WG/CU.
  __shared__ float tile[25][NSd];
  __shared__ float r0l[16][NSd];         // persistent r0 (each thread owns its rows)
  const int tid = threadIdx.x, blk = blockIdx.x;
  const int img = blk & 7, sub = blk >> 3;
  const int y0 = sub*16, bS = img*S;
  const int cg = tid & 127, r0b = tid >> 7, c4o = cg*4;
  const int lane = tid & 63;
  ull* PHq = (ull*)(ws + (size_t)P_PH*NSF);
  ull* VHq = (ull*)(ws + (size_t)P_VH*NSF);
  ull* THq = (ull*)(ws + (size_t)P_TH*NSF);
  ull* Aq  = (ull*)(ws + (size_t)NPLH*NSF);
  ull* Bq  = Aq + A_QW;
  unsigned ep = 0;
  const int kmax = kmp[0];
  const int row0o  = bS + (y0<<9) + c4o;
  const int row15o = bS + ((y0+15)<<9) + c4o;
  const int rowm1o = bS + ((y0-1)<<9) + c4o;   // valid only if sub>0
  const int row16o = bS + ((y0+16)<<9) + c4o;  // valid only if sub<31
  float red[5];

  // ---- setup: coefficients into registers (contiguous rows 4*r0b+k) ----
  float ax_[4][4], axl_[4], by_[4][4], bym0_[4];
  float msum = 0.f;
  #pragma unroll
  for (int k=0;k<4;++k){
    int fy = y0 + 4*r0b + k, ro = bS + (fy<<9);
    float vc[4], vd[4], m1[4], m2[4];
    LD4(vc, Vg+ro+c4o);
    float vr  = Vg[ro + (c4o<508 ? c4o+4 : 511)];
    float vl  = c4o ? Vg[ro+c4o-1]  : vc[0];
    float m1l = c4o ? M1g[ro+c4o-1] : 0.f;
    LD4(vd, Vg + bS + (cl(fy+1)<<9) + c4o);
    LD4(m1, M1g+ro+c4o);
    LD4(m2, M2g+ro+c4o);
    #pragma unroll
    for (int j=0;j<4;++j){
      float vn = (j<3) ? vc[j+1] : vr;
      ax_[k][j] = RX_*((vn-vc[j])/(0.5f*(vn+vc[j])))*m1[j];
      by_[k][j] = RY_*((vd[j]-vc[j])/(0.5f*(vd[j]+vc[j])))*m2[j];
      msum += vc[j];
    }
    axl_[k] = c4o ? RX_*((vc[0]-vl)/(0.5f*(vc[0]+vl)))*m1l : 0.f;
    if (k==0){
      if (fy > 0){
        float vu[4], m2u[4];
        LD4(vu, Vg + bS + ((fy-1)<<9) + c4o);
        LD4(m2u, M2g + bS + ((fy-1)<<9) + c4o);
        #pragma unroll
        for (int j=0;j<4;++j)
          bym0_[j] = RY_*((vc[j]-vu[j])/(0.5f*(vc[j]+vu[j])))*m2u[j];
      } else {
        bym0_[0]=0.f; bym0_[1]=0.f; bym0_[2]=0.f; bym0_[3]=0.f;
      }
    }
  }
  red[0]=msum;
  ++ep; phase_sync(Aq,Bq,img,sub,ep, red, 1);
  const float c = red[0]*(1.0f/262144.0f);

  // ---- init: x=c, p=r=r0 = b - A(c) = -2c(ax-axm+by-bym); r0 -> LDS ----
  float x_[4][4], p_[4][4], r_[4][4], v_[4][4];
  float ph_[4], rh_[4], xh_[4], vh_[4];   // halo-row mirrors (r0b 0/3)
  {
    float pa = 0.f;
    #pragma unroll
    for (int k=0;k<4;++k){
      const float* bymk = k ? by_[k-1] : bym0_;
      float pn4[4];
      #pragma unroll
      for (int j=0;j<4;++j){
        float axm = j ? ax_[k][j-1] : axl_[k];
        float pn = -2.f*c*(ax_[k][j]-axm + by_[k][j]-bymk[j]);
        x_[k][j]=c; p_[k][j]=pn; r_[k][j]=pn; v_[k][j]=0.f;
        pn4[j]=pn;
        pa += pn*pn;
      }
      ST4(&r0l[4*r0b+k][c4o], pn4);
    }
    #pragma unroll
    for (int j=0;j<4;++j){ xh_[j]=c; ph_[j]=0.f; rh_[j]=0.f; vh_[j]=0.f; }
    if (r0b==0) hstore4(PHq, row0o, p_[0]);
    if (r0b==3) hstore4(PHq, row15o, p_[3]);
    red[0]=pa;
    ++ep; phase_sync(Aq,Bq,img,sub,ep, red, 1);
  }
  float rr0 = red[0];
  float r0abs = sqrtf(rr0), rabs = r0abs;
  int kcnt = 0;
  bool c4p = false;
  float alpha=0.f, omega=0.f, beta=0.f;

  for (int it=0; it<kmax; ++it){
    if (!((kcnt < kmax) && (rabs > THR))) break;

    // ================= P1: p-update; v = A(p); <v,r0>, <v,v> =================
    if (c4p){
      #pragma unroll
      for (int k=0;k<4;++k)
        #pragma unroll
        for (int j=0;j<4;++j)
          p_[k][j] = r_[k][j] + beta*(p_[k][j]-omega*v_[k][j]);
      if (r0b==0 || r0b==3){
        #pragma unroll
        for (int j=0;j<4;++j) ph_[j] = rh_[j] + beta*(ph_[j]-omega*vh_[j]);
      }
    } else {
      // after init/restart: r==p; refresh mirrors from PH (or own row)
      if (r0b==0){
        if (sub==0){ CP4(ph_, p_[0]); } else hload4(PHq, rowm1o, ph_);
        CP4(rh_, ph_);
      }
      if (r0b==3){
        if (sub==IPB-1){ CP4(ph_, p_[3]); } else hload4(PHq, row16o, ph_);
        CP4(rh_, ph_);
      }
    }
    #pragma unroll
    for (int k=0;k<4;++k){ ST4(&tile[4*r0b+k+1][c4o], p_[k]); }
    if (r0b==0) ST4(&tile[0][c4o], ph_);
    if (r0b==3) ST4(&tile[17][c4o], ph_);
    __syncthreads();
    {
      float s1=0.f, s2=0.f;
      #pragma unroll
      for (int k=0;k<4;++k){
        int st = 4*r0b+k+1;
        const float* bymk = k ? by_[k-1] : bym0_;
        float zu[4], zd[4], ov[4], r0v[4];
        LD4(zu, &tile[st-1][c4o]);
        LD4(zd, &tile[st+1][c4o]);
        LD4(r0v, &r0l[4*r0b+k][c4o]);
        float zl = __shfl_up(p_[k][3], 1);
        float zr = __shfl_down(p_[k][0], 1);
        if (lane==0)  zl = (c4o==0)   ? p_[k][0] : tile[st][c4o-1];
        if (lane==63) zr = (c4o==508) ? p_[k][3] : tile[st][c4o+4];
        stencil_reg(p_[k], zl, zr, zu, zd, ax_[k], axl_[k], by_[k], bymk, ov);
        #pragma unroll
        for (int j=0;j<4;++j){
          v_[k][j]=ov[j]; s1 += ov[j]*r0v[j]; s2 += ov[j]*ov[j];
        }
      }
      if (r0b==0) hstore4(VHq, row0o, v_[0]);
      if (r0b==3) hstore4(VHq, row15o, v_[3]);
      red[0]=s1; red[1]=s2;
      ++ep; phase_sync(Aq,Bq,img,sub,ep, red, 2);
    }
    float sig = red[0], vabs = sqrtf(red[1]);

    if (sig <= EPSF*vabs*r0abs){
      // ---- restart: p = r = r0 = b - A(x) ----
      #pragma unroll
      for (int k=0;k<4;++k){ ST4(&tile[4*r0b+k+1][c4o], x_[k]); }
      if (r0b==0) ST4(&tile[0][c4o], xh_);
      if (r0b==3) ST4(&tile[17][c4o], xh_);
      __syncthreads();
      float pa = 0.f;
      #pragma unroll
      for (int k=0;k<4;++k){
        int st = 4*r0b+k+1;
        const float* bymk = k ? by_[k-1] : bym0_;
        float zu[4], zd[4], av[4], pn4[4];
        LD4(zu, &tile[st-1][c4o]);
        LD4(zd, &tile[st+1][c4o]);
        float zl = __shfl_up(x_[k][3], 1);
        float zr = __shfl_down(x_[k][0], 1);
        if (lane==0)  zl = (c4o==0)   ? x_[k][0] : tile[st][c4o-1];
        if (lane==63) zr = (c4o==508) ? x_[k][3] : tile[st][c4o+4];
        stencil_reg(x_[k], zl, zr, zu, zd, ax_[k], axl_[k], by_[k], bymk, av);
        #pragma unroll
        for (int j=0;j<4;++j){
          float pn = c - av[j];
          p_[k][j]=pn; r_[k][j]=pn; pn4[j]=pn;
          pa += pn*pn;
        }
        ST4(&r0l[4*r0b+k][c4o], pn4);
      }
      if (r0b==0) hstore4(PHq, row0o, p_[0]);
      if (r0b==3) hstore4(PHq, row15o, p_[3]);
      red[0]=pa;
      ++ep; phase_sync(Aq,Bq,img,sub,ep, red, 1);
      rr0 = red[0]; r0abs = sqrtf(rr0); rabs = r0abs; kcnt++;
      c4p = false;
      continue;
    }

    // ================= P2: s; t=A(s); 5 sums (c4 folded in) =================
    alpha = rr0 / sig;
    if (r0b==0){
      if (sub==0){ CP4(vh_, v_[0]); } else hload4(VHq, rowm1o, vh_);
    }
    if (r0b==3){
      if (sub==IPB-1){ CP4(vh_, v_[3]); } else hload4(VHq, row16o, vh_);
    }
    float t0s[4], t3s[4];
    {
      float ssp = 0.f;
      #pragma unroll
      for (int k=0;k<4;++k){
        float sv[4];
        #pragma unroll
        for (int j=0;j<4;++j){
          sv[j] = r_[k][j] - alpha*v_[k][j];
          ssp += sv[j]*sv[j];
        }
        ST4(&tile[4*r0b+k+1][c4o], sv);
      }
      if (r0b==0){
        float sh[4];
        #pragma unroll
        for (int j=0;j<4;++j) sh[j] = rh_[j] - alpha*vh_[j];
        ST4(&tile[0][c4o], sh);
      }
      if (r0b==3){
        float sh[4];
        #pragma unroll
        for (int j=0;j<4;++j) sh[j] = rh_[j] - alpha*vh_[j];
        ST4(&tile[17][c4o], sh);
      }
      __syncthreads();
      float tsp=0.f, ttp=0.f, sr0p=0.f, tr0p=0.f;
      #pragma unroll
      for (int k=0;k<4;++k){
        int st = 4*r0b+k+1;
        const float* bymk = k ? by_[k-1] : bym0_;
        float zc[4], zu[4], zd[4], tv[4], r0v[4];
        #pragma unroll
        for (int j=0;j<4;++j) zc[j] = r_[k][j] - alpha*v_[k][j];
        LD4(zu, &tile[st-1][c4o]);
        LD4(zd, &tile[st+1][c4o]);
        LD4(r0v, &r0l[4*r0b+k][c4o]);
        float zl = __shfl_up(zc[3], 1);
        float zr = __shfl_down(zc[0], 1);
        if (lane==0)  zl = (c4o==0)   ? zc[0] : tile[st][c4o-1];
        if (lane==63) zr = (c4o==508) ? zc[3] : tile[st][c4o+4];
        stencil_reg(zc, zl, zr, zu, zd, ax_[k], axl_[k], by_[k], bymk, tv);
        #pragma unroll
        for (int j=0;j<4;++j){
          tsp  += tv[j]*zc[j];
          ttp  += tv[j]*tv[j];
          sr0p += zc[j]*r0v[j];
          tr0p += tv[j]*r0v[j];
        }
        if (k==0){ CP4(t0s, tv); }
        if (k==3){ CP4(t3s, tv); }
      }
      if (r0b==0) hstore4(THq, row0o, t0s);
      if (r0b==3) hstore4(THq, row15o, t3s);
      red[0]=ssp; red[1]=tsp; red[2]=ttp; red[3]=sr0p; red[4]=tr0p;
      ++ep; phase_sync(Aq,Bq,img,sub,ep, red, 5);
    }
    float ss=red[0], ts=red[1], tt=red[2], s_r0=red[3], t_r0=red[4];
    float snorm = sqrtf(ss);

    if (snorm <= THR){
      // ---- c3: x += alpha*p; loop exits on next check ----
      #pragma unroll
      for (int k=0;k<4;++k)
        #pragma unroll
        for (int j=0;j<4;++j) x_[k][j] += alpha*p_[k][j];
      rabs = snorm; kcnt++; c4p = false;
      continue;
    }

    // ---- c4 (local): x += alpha*p + omega*s; r = s - omega*t ----
    omega = ts/tt;
    #pragma unroll
    for (int k=0;k<4;++k){
      int st = 4*r0b+k+1;
      const float* bymk = k ? by_[k-1] : bym0_;
      float zc[4], zu[4], zd[4], tv[4];
      #pragma unroll
      for (int j=0;j<4;++j) zc[j] = r_[k][j] - alpha*v_[k][j];
      LD4(zu, &tile[st-1][c4o]);
      LD4(zd, &tile[st+1][c4o]);
      float zl = __shfl_up(zc[3], 1);
      float zr = __shfl_down(zc[0], 1);
      if (lane==0)  zl = (c4o==0)   ? zc[0] : tile[st][c4o-1];
      if (lane==63) zr = (c4o==508) ? zc[3] : tile[st][c4o+4];
      stencil_reg(zc, zl, zr, zu, zd, ax_[k], axl_[k], by_[k], bymk, tv);
      #pragma unroll
      for (int j=0;j<4;++j){
        x_[k][j] = x_[k][j] + alpha*p_[k][j] + omega*zc[j];
        r_[k][j] = zc[j] - omega*tv[j];
      }
    }
    // halo mirror updates (r,x at rows -1 / 16)
    if (r0b==0){
      float th[4];
      if (sub==0){ CP4(th, t0s); } else hload4(THq, rowm1o, th);
      #pragma unroll
      for (int j=0;j<4;++j){
        float sh = rh_[j] - alpha*vh_[j];
        xh_[j] = xh_[j] + alpha*ph_[j] + omega*sh;
        rh_[j] = sh - omega*th[j];
      }
    }
    if (r0b==3){
      float th[4];
      if (sub==IPB-1){ CP4(th, t3s); } else hload4(THq, row16o, th);
      #pragma unroll
      for (int j=0;j<4;++j){
        float sh = rh_[j] - alpha*vh_[j];
        xh_[j] = xh_[j] + alpha*ph_[j] + omega*sh;
        rh_[j] = sh - omega*th[j];
      }
    }
    float rr0n = s_r0 - omega*t_r0;
    rabs = sqrtf(fmaxf(ss - 2.f*omega*ts + omega*omega*tt, 0.f));
    beta = alpha/omega*(rr0n/rr0);
    rr0 = rr0n; kcnt++;
    c4p = true;
  }

  // ---- pack: out[img][i][j]: border=c, interior = x[j-1][i-1] ----
  __syncthreads();
  float* lp = &tile[0][0];                  // reused as [16][516]
  #pragma unroll
  for (int k=0;k<4;++k){
    int ri = 4*r0b + k;
    ST4(lp + ri*516 + c4o, x_[k]);
  }
  float* outb = outg + (size_t)img*PADS*PADS;
  if (sub == 0){
    for (int e = tid; e < 2052; e += NT){
      int i, j;
      if (e < 514)      { i=0;        j=e;      }
      else if (e < 1028){ i=513;      j=e-514;  }
      else if (e < 1540){ i=e-1028+1; j=0;      }
      else              { i=e-1540+1; j=513;    }
      outb[i*PADS+j] = c;
    }
  }
  __syncthreads();
  {
    int qq = tid & 15, xb = tid >> 4;       // 16 rows x 32 col-groups
    #pragma unroll
    for (int ps=0; ps<16; ++ps){
      int xc = ps*32 + xb;
      outb[(size_t)(xc+1)*PADS + (y0+1+qq)] = lp[qq*516 + xc];
    }
  }
}

} // namespace

extern "C" void kernel_launch(void* const* d_in, const int* in_sizes, int n_in,
                              void* d_out, int out_size, void* d_ws, size_t ws_size,
                              hipStream_t stream){
  const float* V  = (const float*)d_in[0];
  const float* M1 = (const float*)d_in[1];
  const float* M2 = (const float*)d_in[2];
  const int*   km = (const int*)d_in[3];
  float* ws  = (float*)d_ws;
  float* out = (float*)d_out;

  size_t need = (size_t)NPLH*NSF*sizeof(float) + (A_QW + B_QW)*sizeof(ull);
  if (ws_size < need) return;

  // zero the slot/broadcast region each call (graph-capturable)
  hipMemsetAsync((char*)d_ws + (size_t)NPLH*NSF*sizeof(float),
                 0, (A_QW + B_QW)*sizeof(ull), stream);

  solve<<<dim3(NB), dim3(NT), 0, stream>>>(V, M1, M2, km, out, ws);
}

// Round 13
// 210.506 us; speedup vs baseline: 2.5247x; 1.4972x over previous
//
#include <hip/hip_runtime.h>
#include <math.h>

// BiCGStab, 8 independent 512x512 images, single persistent kernel.
// 256 blocks x 512 threads. LDS 135KB/block => 1 WG/CU pinned; grid 256 =
// #CUs => unconditional residency (spin sync deadlock-free).
// KEY: live register set < 128 (the allocator's hard budget): coefficients
// (ax/by) AND r0 live in LDS planes; only x,p,r,v + halo mirrors in regs
// => zero scratch spills. s in LDS tile; t recomputed.
// TWO syncs/iteration (c4 dots folded into P2 algebraically).
// Sync: fence-free aggregator protocol (round-8 validated).

namespace {

typedef unsigned long long ull;

constexpr int NIMG = 8;
constexpr int NSd  = 512;
constexpr int S    = NSd*NSd;
constexpr int NSF  = NIMG*S;
constexpr int PADS = 514;
constexpr int NB   = 256;
constexpr int IPB  = 32;     // blocks per image
constexpr int NT   = 512;
constexpr float EPSF = 1e-9f;
constexpr float THR  = 1e-9f * 262144.0f;
constexpr float RX_=50.f, RY_=50.f, RXX_=100.f, RYY_=100.f;
constexpr float BOO0 = 1.f + 2.f*(RXX_+RYY_);

enum { P_PH=0, P_VH, P_TH, NPLH };                 // halo planes (atomic qwords)
constexpr size_t A_QW = (size_t)NIMG*2*8*32;       // 4096 qwords (32 KB)
constexpr size_t B_QW = (size_t)NIMG*2*8;          // 128 qwords (1 KB)

__device__ __forceinline__ int cl(int i){ return i<0?0:(i>NSd-1?NSd-1:i); }

#define LD4(d, p) { float4 _t4 = *reinterpret_cast<const float4*>(p); \
  (d)[0]=_t4.x; (d)[1]=_t4.y; (d)[2]=_t4.z; (d)[3]=_t4.w; }
#define ST4(p, s) { *reinterpret_cast<float4*>(p) = \
  make_float4((s)[0],(s)[1],(s)[2],(s)[3]); }
#define CP4(d, s) { (d)[0]=(s)[0]; (d)[1]=(s)[1]; (d)[2]=(s)[2]; (d)[3]=(s)[3]; }

// load per-row coefficients from LDS planes (rr = block-local row 0..15)
#define LOADCOEF(rr_) \
  float ax[4], by[4], bym[4], axl; \
  LD4(ax, &axp[rr_][c4o]); \
  axl = c4o ? axp[rr_][c4o-1] : 0.f; \
  LD4(by, &byp[rr_][c4o]); \
  if ((rr_) > 0){ LD4(bym, &byp[(rr_)-1][c4o]); } else { CP4(bym, bym0_); }

// ---- coherent halo row I/O (relaxed agent atomics, 2 floats per qword) ----
__device__ __forceinline__ void hstore4(ull* pq, int off_f, const float s[4]){
  size_t q = (size_t)off_f >> 1;
  ull u0 = ((ull)__float_as_uint(s[1])<<32) | (ull)__float_as_uint(s[0]);
  ull u1 = ((ull)__float_as_uint(s[3])<<32) | (ull)__float_as_uint(s[2]);
  __hip_atomic_store(pq+q,   u0, __ATOMIC_RELAXED, __HIP_MEMORY_SCOPE_AGENT);
  __hip_atomic_store(pq+q+1, u1, __ATOMIC_RELAXED, __HIP_MEMORY_SCOPE_AGENT);
}
__device__ __forceinline__ void hload4(const ull* pq, int off_f, float d[4]){
  size_t q = (size_t)off_f >> 1;
  ull u0 = __hip_atomic_load(pq+q,   __ATOMIC_RELAXED, __HIP_MEMORY_SCOPE_AGENT);
  ull u1 = __hip_atomic_load(pq+q+1, __ATOMIC_RELAXED, __HIP_MEMORY_SCOPE_AGENT);
  d[0]=__uint_as_float((unsigned)u0); d[1]=__uint_as_float((unsigned)(u0>>32));
  d[2]=__uint_as_float((unsigned)u1); d[3]=__uint_as_float((unsigned)(u1>>32));
}

// ---- aggregator phase sync: post -> (sub0 reduces+publishes) -> broadcast ----
__device__ __forceinline__ void phase_sync(ull* Aq, ull* Bq, int img, int sub,
    unsigned ep, float* v, int n){
  __shared__ float acc[8][5];
  __shared__ float bc[5];
  const int tid = threadIdx.x, w = tid>>6, lane = tid&63;
  #pragma unroll
  for (int i=0;i<5;++i){
    if (i<n){
      float a = v[i];
      #pragma unroll
      for (int o=32;o;o>>=1) a += __shfl_xor(a,o);
      if (lane==0) acc[w][i] = a;
    }
  }
  __syncthreads();   // acc ready; drains vmcnt (halo stores globally visible)
  const int par = ep & 1;
  ull* Ab = Aq + ((size_t)(img*2+par)*8)*32;   // [sum][32] qwords, 256B rows
  ull* Bb = Bq + ((size_t)(img*2+par))*8;      // one 64B line
  if (sub == 0){
    if (w < n){
      float own = 0.f;
      #pragma unroll
      for (int i=0;i<8;++i) own += acc[i][w];
      ull x = 0; const bool me = (lane>=1 && lane<32);
      for(;;){
        bool ok = true;
        if (me){
          x = __hip_atomic_load(Ab + w*32 + lane, __ATOMIC_RELAXED, __HIP_MEMORY_SCOPE_AGENT);
          ok = ((unsigned)x == ep);
        }
        if (__all(ok)) break;
        __builtin_amdgcn_s_sleep(2);
      }
      float a = me ? __uint_as_float((unsigned)(x>>32)) : ((lane==0)? own : 0.f);
      #pragma unroll
      for (int o=16;o;o>>=1) a += __shfl_xor(a,o);   // lanes 0..31
      if (lane==0){
        bc[w] = a;
        ull pk = ((ull)__float_as_uint(a)<<32) | (ull)ep;
        __hip_atomic_store(Bb + w, pk, __ATOMIC_RELAXED, __HIP_MEMORY_SCOPE_AGENT);
      }
    }
  } else {
    if (tid < n){
      float t = 0.f;
      #pragma unroll
      for (int i=0;i<8;++i) t += acc[i][tid];
      ull pk = ((ull)__float_as_uint(t)<<32) | (ull)ep;
      __hip_atomic_store(Ab + tid*32 + sub, pk, __ATOMIC_RELAXED, __HIP_MEMORY_SCOPE_AGENT);
    }
    if (w == 0){
      ull x = 0; const bool me = (lane < n);
      for(;;){
        bool ok = true;
        if (me){
          x = __hip_atomic_load(Bb + lane, __ATOMIC_RELAXED, __HIP_MEMORY_SCOPE_AGENT);
          ok = ((unsigned)x == ep);
        }
        if (__all(ok)) break;
        __builtin_amdgcn_s_sleep(2);
      }
      if (me) bc[lane] = __uint_as_float((unsigned)(x>>32));
    }
  }
  __syncthreads();
  #pragma unroll
  for (int i=0;i<5;++i) if (i<n) v[i] = bc[i];
}

// 5-point stencil, center strip from registers; reference summation order
__device__ __forceinline__ void stencil_reg(const float zc[4], float zl, float zr,
    const float zu[4], const float zd[4],
    const float ax[4], float axl, const float by[4], const float bym[4],
    float out[4]){
  #pragma unroll
  for (int j=0;j<4;++j){
    float axm = j ? ax[j-1] : axl;
    float zxm = j ? zc[j-1] : zl;
    float zxp = (j<3) ? zc[j+1] : zr;
    float boo = BOO0 + ax[j] - axm + by[j] - bym[j];
    out[j] = boo*zc[j] + (-RXX_-axm)*zxm + (-RYY_-bym[j])*zu[j]
           + (-RYY_+by[j])*zd[j] + (-RXX_+ax[j])*zxp;
  }
}

__global__ void __launch_bounds__(NT)
solve(const float* __restrict__ Vg,
    const float* __restrict__ M1g, const float* __restrict__ M2g,
    const int* __restrict__ kmp, float* __restrict__ outg, float* __restrict__ ws){
  // 18+16+16+16 = 66 rows x 512 x 4B = 135168 B => 1 WG/CU (pinned).
  __shared__ float tile[18][NSd];
  __shared__ float r0l[16][NSd];
  __shared__ float axp[16][NSd];
  __shared__ float byp[16][NSd];
  const int tid = threadIdx.x, blk = blockIdx.x;
  const int img = blk & 7, sub = blk >> 3;
  const int y0 = sub*16, bS = img*S;
  const int cg = tid & 127, r0b = tid >> 7, c4o = cg*4;
  const int lane = tid & 63;
  ull* PHq = (ull*)(ws + (size_t)P_PH*NSF);
  ull* VHq = (ull*)(ws + (size_t)P_VH*NSF);
  ull* THq = (ull*)(ws + (size_t)P_TH*NSF);
  ull* Aq  = (ull*)(ws + (size_t)NPLH*NSF);
  ull* Bq  = Aq + A_QW;
  unsigned ep = 0;
  const int kmax = kmp[0];
  const int row0o  = bS + (y0<<9) + c4o;
  const int row15o = bS + ((y0+15)<<9) + c4o;
  const int rowm1o = bS + ((y0-1)<<9) + c4o;   // valid only if sub>0
  const int row16o = bS + ((y0+16)<<9) + c4o;  // valid only if sub<31
  float red[5];

  // ---- setup: coefficients into LDS planes + mean partial ----
  float bym0_[4];
  float msum = 0.f;
  #pragma unroll
  for (int k=0;k<4;++k){
    int rr = 4*r0b + k, fy = y0 + rr, ro = bS + (fy<<9);
    float vc[4], vd[4], m1[4], m2[4], ca[4], cb[4];
    LD4(vc, Vg+ro+c4o);
    float vr  = Vg[ro + (c4o<508 ? c4o+4 : 511)];
    LD4(vd, Vg + bS + (cl(fy+1)<<9) + c4o);
    LD4(m1, M1g+ro+c4o);
    LD4(m2, M2g+ro+c4o);
    #pragma unroll
    for (int j=0;j<4;++j){
      float vn = (j<3) ? vc[j+1] : vr;
      ca[j] = RX_*((vn-vc[j])/(0.5f*(vn+vc[j])))*m1[j];
      cb[j] = RY_*((vd[j]-vc[j])/(0.5f*(vd[j]+vc[j])))*m2[j];
      msum += vc[j];
    }
    ST4(&axp[rr][c4o], ca);
    ST4(&byp[rr][c4o], cb);
  }
  if (r0b==0 && sub>0){
    int ro = bS + (y0<<9);
    float vc[4], vu[4], m2u[4];
    LD4(vc, Vg+ro+c4o);
    LD4(vu, Vg + bS + ((y0-1)<<9) + c4o);
    LD4(m2u, M2g + bS + ((y0-1)<<9) + c4o);
    #pragma unroll
    for (int j=0;j<4;++j)
      bym0_[j] = RY_*((vc[j]-vu[j])/(0.5f*(vc[j]+vu[j])))*m2u[j];
  } else {
    bym0_[0]=0.f; bym0_[1]=0.f; bym0_[2]=0.f; bym0_[3]=0.f;
  }
  red[0]=msum;
  ++ep; phase_sync(Aq,Bq,img,sub,ep, red, 1);   // also fences LDS planes
  const float c = red[0]*(1.0f/262144.0f);

  // ---- init: x=c, p=r=r0 = b - A(c) = -2c(ax-axm+by-bym); r0 -> LDS ----
  float x_[4][4], p_[4][4], r_[4][4], v_[4][4];
  float ph_[4], rh_[4], xh_[4], vh_[4];   // halo-row mirrors (r0b 0/3)
  {
    float pa = 0.f;
    #pragma unroll
    for (int k=0;k<4;++k){
      int rr = 4*r0b + k;
      LOADCOEF(rr);
      float pn4[4];
      #pragma unroll
      for (int j=0;j<4;++j){
        float axm = j ? ax[j-1] : axl;
        float pn = -2.f*c*(ax[j]-axm + by[j]-bym[j]);
        x_[k][j]=c; p_[k][j]=pn; r_[k][j]=pn; v_[k][j]=0.f;
        pn4[j]=pn;
        pa += pn*pn;
      }
      ST4(&r0l[rr][c4o], pn4);
    }
    #pragma unroll
    for (int j=0;j<4;++j){ xh_[j]=c; ph_[j]=0.f; rh_[j]=0.f; vh_[j]=0.f; }
    if (r0b==0) hstore4(PHq, row0o, p_[0]);
    if (r0b==3) hstore4(PHq, row15o, p_[3]);
    red[0]=pa;
    ++ep; phase_sync(Aq,Bq,img,sub,ep, red, 1);
  }
  float rr0 = red[0];
  float r0abs = sqrtf(rr0), rabs = r0abs;
  int kcnt = 0;
  bool c4p = false;
  float alpha=0.f, omega=0.f, beta=0.f;

  for (int it=0; it<kmax; ++it){
    if (!((kcnt < kmax) && (rabs > THR))) break;

    // ================= P1: p-update; v = A(p); <v,r0>, <v,v> =================
    if (c4p){
      #pragma unroll
      for (int k=0;k<4;++k)
        #pragma unroll
        for (int j=0;j<4;++j)
          p_[k][j] = r_[k][j] + beta*(p_[k][j]-omega*v_[k][j]);
      if (r0b==0 || r0b==3){
        #pragma unroll
        for (int j=0;j<4;++j) ph_[j] = rh_[j] + beta*(ph_[j]-omega*vh_[j]);
      }
    } else {
      // after init/restart: r==p; refresh mirrors from PH (or own row)
      if (r0b==0){
        if (sub==0){ CP4(ph_, p_[0]); } else hload4(PHq, rowm1o, ph_);
        CP4(rh_, ph_);
      }
      if (r0b==3){
        if (sub==IPB-1){ CP4(ph_, p_[3]); } else hload4(PHq, row16o, ph_);
        CP4(rh_, ph_);
      }
    }
    #pragma unroll
    for (int k=0;k<4;++k){ ST4(&tile[4*r0b+k+1][c4o], p_[k]); }
    if (r0b==0) ST4(&tile[0][c4o], ph_);
    if (r0b==3) ST4(&tile[17][c4o], ph_);
    __syncthreads();
    {
      float s1=0.f, s2=0.f;
      #pragma unroll
      for (int k=0;k<4;++k){
        int rr = 4*r0b+k, st = rr+1;
        LOADCOEF(rr);
        float zu[4], zd[4], ov[4], r0v[4];
        LD4(zu, &tile[st-1][c4o]);
        LD4(zd, &tile[st+1][c4o]);
        LD4(r0v, &r0l[rr][c4o]);
        float zl = __shfl_up(p_[k][3], 1);
        float zr = __shfl_down(p_[k][0], 1);
        if (lane==0)  zl = (c4o==0)   ? p_[k][0] : tile[st][c4o-1];
        if (lane==63) zr = (c4o==508) ? p_[k][3] : tile[st][c4o+4];
        stencil_reg(p_[k], zl, zr, zu, zd, ax, axl, by, bym, ov);
        #pragma unroll
        for (int j=0;j<4;++j){
          v_[k][j]=ov[j]; s1 += ov[j]*r0v[j]; s2 += ov[j]*ov[j];
        }
      }
      if (r0b==0) hstore4(VHq, row0o, v_[0]);
      if (r0b==3) hstore4(VHq, row15o, v_[3]);
      red[0]=s1; red[1]=s2;
      ++ep; phase_sync(Aq,Bq,img,sub,ep, red, 2);
    }
    float sig = red[0], vabs = sqrtf(red[1]);

    if (sig <= EPSF*vabs*r0abs){
      // ---- restart: p = r = r0 = b - A(x) ----
      #pragma unroll
      for (int k=0;k<4;++k){ ST4(&tile[4*r0b+k+1][c4o], x_[k]); }
      if (r0b==0) ST4(&tile[0][c4o], xh_);
      if (r0b==3) ST4(&tile[17][c4o], xh_);
      __syncthreads();
      float pa = 0.f;
      #pragma unroll
      for (int k=0;k<4;++k){
        int rr = 4*r0b+k, st = rr+1;
        LOADCOEF(rr);
        float zu[4], zd[4], av[4], pn4[4];
        LD4(zu, &tile[st-1][c4o]);
        LD4(zd, &tile[st+1][c4o]);
        float zl = __shfl_up(x_[k][3], 1);
        float zr = __shfl_down(x_[k][0], 1);
        if (lane==0)  zl = (c4o==0)   ? x_[k][0] : tile[st][c4o-1];
        if (lane==63) zr = (c4o==508) ? x_[k][3] : tile[st][c4o+4];
        stencil_reg(x_[k], zl, zr, zu, zd, ax, axl, by, bym, av);
        #pragma unroll
        for (int j=0;j<4;++j){
          float pn = c - av[j];
          p_[k][j]=pn; r_[k][j]=pn; pn4[j]=pn;
          pa += pn*pn;
        }
        ST4(&r0l[rr][c4o], pn4);
      }
      if (r0b==0) hstore4(PHq, row0o, p_[0]);
      if (r0b==3) hstore4(PHq, row15o, p_[3]);
      red[0]=pa;
      ++ep; phase_sync(Aq,Bq,img,sub,ep, red, 1);
      rr0 = red[0]; r0abs = sqrtf(rr0); rabs = r0abs; kcnt++;
      c4p = false;
      continue;
    }

    // ================= P2: s; t=A(s); 5 sums (c4 folded in) =================
    alpha = rr0 / sig;
    if (r0b==0){
      if (sub==0){ CP4(vh_, v_[0]); } else hload4(VHq, rowm1o, vh_);
    }
    if (r0b==3){
      if (sub==IPB-1){ CP4(vh_, v_[3]); } else hload4(VHq, row16o, vh_);
    }
    float t0s[4], t3s[4];
    {
      float ssp = 0.f;
      #pragma unroll
      for (int k=0;k<4;++k){
        float sv[4];
        #pragma unroll
        for (int j=0;j<4;++j){
          sv[j] = r_[k][j] - alpha*v_[k][j];
          ssp += sv[j]*sv[j];
        }
        ST4(&tile[4*r0b+k+1][c4o], sv);
      }
      if (r0b==0){
        float sh[4];
        #pragma unroll
        for (int j=0;j<4;++j) sh[j] = rh_[j] - alpha*vh_[j];
        ST4(&tile[0][c4o], sh);
      }
      if (r0b==3){
        float sh[4];
        #pragma unroll
        for (int j=0;j<4;++j) sh[j] = rh_[j] - alpha*vh_[j];
        ST4(&tile[17][c4o], sh);
      }
      __syncthreads();
      float tsp=0.f, ttp=0.f, sr0p=0.f, tr0p=0.f;
      #pragma unroll
      for (int k=0;k<4;++k){
        int rr = 4*r0b+k, st = rr+1;
        LOADCOEF(rr);
        float zc[4], zu[4], zd[4], tv[4], r0v[4];
        #pragma unroll
        for (int j=0;j<4;++j) zc[j] = r_[k][j] - alpha*v_[k][j];
        LD4(zu, &tile[st-1][c4o]);
        LD4(zd, &tile[st+1][c4o]);
        LD4(r0v, &r0l[rr][c4o]);
        float zl = __shfl_up(zc[3], 1);
        float zr = __shfl_down(zc[0], 1);
        if (lane==0)  zl = (c4o==0)   ? zc[0] : tile[st][c4o-1];
        if (lane==63) zr = (c4o==508) ? zc[3] : tile[st][c4o+4];
        stencil_reg(zc, zl, zr, zu, zd, ax, axl, by, bym, tv);
        #pragma unroll
        for (int j=0;j<4;++j){
          tsp  += tv[j]*zc[j];
          ttp  += tv[j]*tv[j];
          sr0p += zc[j]*r0v[j];
          tr0p += tv[j]*r0v[j];
        }
        if (k==0){ CP4(t0s, tv); }
        if (k==3){ CP4(t3s, tv); }
      }
      if (r0b==0) hstore4(THq, row0o, t0s);
      if (r0b==3) hstore4(THq, row15o, t3s);
      red[0]=ssp; red[1]=tsp; red[2]=ttp; red[3]=sr0p; red[4]=tr0p;
      ++ep; phase_sync(Aq,Bq,img,sub,ep, red, 5);
    }
    float ss=red[0], ts=red[1], tt=red[2], s_r0=red[3], t_r0=red[4];
    float snorm = sqrtf(ss);

    if (snorm <= THR){
      // ---- c3: x += alpha*p; loop exits on next check ----
      #pragma unroll
      for (int k=0;k<4;++k)
        #pragma unroll
        for (int j=0;j<4;++j) x_[k][j] += alpha*p_[k][j];
      rabs = snorm; kcnt++; c4p = false;
      continue;
    }

    // ---- c4 (local): x += alpha*p + omega*s; r = s - omega*t ----
    omega = ts/tt;
    #pragma unroll
    for (int k=0;k<4;++k){
      int rr = 4*r0b+k, st = rr+1;
      LOADCOEF(rr);
      float zc[4], zu[4], zd[4], tv[4];
      #pragma unroll
      for (int j=0;j<4;++j) zc[j] = r_[k][j] - alpha*v_[k][j];
      LD4(zu, &tile[st-1][c4o]);
      LD4(zd, &tile[st+1][c4o]);
      float zl = __shfl_up(zc[3], 1);
      float zr = __shfl_down(zc[0], 1);
      if (lane==0)  zl = (c4o==0)   ? zc[0] : tile[st][c4o-1];
      if (lane==63) zr = (c4o==508) ? zc[3] : tile[st][c4o+4];
      stencil_reg(zc, zl, zr, zu, zd, ax, axl, by, bym, tv);
      #pragma unroll
      for (int j=0;j<4;++j){
        x_[k][j] = x_[k][j] + alpha*p_[k][j] + omega*zc[j];
        r_[k][j] = zc[j] - omega*tv[j];
      }
    }
    // halo mirror updates (r,x at rows -1 / 16)
    if (r0b==0){
      float th[4];
      if (sub==0){ CP4(th, t0s); } else hload4(THq, rowm1o, th);
      #pragma unroll
      for (int j=0;j<4;++j){
        float sh = rh_[j] - alpha*vh_[j];
        xh_[j] = xh_[j] + alpha*ph_[j] + omega*sh;
        rh_[j] = sh - omega*th[j];
      }
    }
    if (r0b==3){
      float th[4];
      if (sub==IPB-1){ CP4(th, t3s); } else hload4(THq, row16o, th);
      #pragma unroll
      for (int j=0;j<4;++j){
        float sh = rh_[j] - alpha*vh_[j];
        xh_[j] = xh_[j] + alpha*ph_[j] + omega*sh;
        rh_[j] = sh - omega*th[j];
      }
    }
    float rr0n = s_r0 - omega*t_r0;
    rabs = sqrtf(fmaxf(ss - 2.f*omega*ts + omega*omega*tt, 0.f));
    beta = alpha/omega*(rr0n/rr0);
    rr0 = rr0n; kcnt++;
    c4p = true;
  }

  // ---- pack: out[img][i][j]: border=c, interior = x[j-1][i-1] ----
  __syncthreads();
  float* lp = &tile[0][0];                  // reused as [16][516] (33024B fits)
  #pragma unroll
  for (int k=0;k<4;++k){
    int ri = 4*r0b + k;
    ST4(lp + ri*516 + c4o, x_[k]);
  }
  float* outb = outg + (size_t)img*PADS*PADS;
  if (sub == 0){
    for (int e = tid; e < 2052; e += NT){
      int i, j;
      if (e < 514)      { i=0;        j=e;      }
      else if (e < 1028){ i=513;      j=e-514;  }
      else if (e < 1540){ i=e-1028+1; j=0;      }
      else              { i=e-1540+1; j=513;    }
      outb[i*PADS+j] = c;
    }
  }
  __syncthreads();
  {
    int qq = tid & 15, xb = tid >> 4;       // 16 rows x 32 col-groups
    #pragma unroll
    for (int ps=0; ps<16; ++ps){
      int xc = ps*32 + xb;
      outb[(size_t)(xc+1)*PADS + (y0+1+qq)] = lp[qq*516 + xc];
    }
  }
}

} // namespace

extern "C" void kernel_launch(void* const* d_in, const int* in_sizes, int n_in,
                              void* d_out, int out_size, void* d_ws, size_t ws_size,
                              hipStream_t stream){
  const float* V  = (const float*)d_in[0];
  const float* M1 = (const float*)d_in[1];
  const float* M2 = (const float*)d_in[2];
  const int*   km = (const int*)d_in[3];
  float* ws  = (float*)d_ws;
  float* out = (float*)d_out;

  size_t need = (size_t)NPLH*NSF*sizeof(float) + (A_QW + B_QW)*sizeof(ull);
  if (ws_size < need) return;

  // zero the slot/broadcast region each call (graph-capturable)
  hipMemsetAsync((char*)d_ws + (size_t)NPLH*NSF*sizeof(float),
                 0, (A_QW + B_QW)*sizeof(ull), stream);

  solve<<<dim3(NB), dim3(NT), 0, stream>>>(V, M1, M2, km, out, ws);
}